// Round 1
// 330.132 us; speedup vs baseline: 1.2106x; 1.2106x over previous
//
#include <hip/hip_runtime.h>
#include <stdint.h>

#define EPSF 1e-20f

typedef __attribute__((ext_vector_type(4))) int i32x4;
typedef __attribute__((ext_vector_type(8))) int i32x8;
typedef __attribute__((ext_vector_type(16))) float f32x16;

// ===========================================================================
// PATH A (primary): binarize to ±1 FP4 (e2m1) + mfma_scale f8f6f4 GEMM.
// ±1 is exact in e2m1 (+1=0x2, -1=0xA); scales forced to 1.0 (e8m0 0x7F).
// FP4 MFMA rate is 2.07x the i8 rate at identical cycles/instr, and the
// kernel geometry (BK = 256 fp4 elem = 128 B/row) is byte-identical to the
// previous i8 version — only the K trip count halves (32 -> 16).
// ===========================================================================

// fp32 -> packed fp4 nibbles, 8 floats per u32. Thread handles 4 outputs
// (reads 128 B, writes 16 B). Stores are 4B/lane coalesced.
__global__ __launch_bounds__(256)
void bin_fp4_kernel(const float4* __restrict__ src, uint32_t* __restrict__ dst,
                    int n8) {
    int base = blockIdx.x * 1024 + threadIdx.x;   // u32 output index
#pragma unroll
    for (int j = 0; j < 4; ++j) {
        int idx = base + j * 256;
        if (idx < n8) {
            float4 v0 = src[2 * idx];
            float4 v1 = src[2 * idx + 1];
            // e2m1: +1.0 = 0b0010, -1.0 = 0b1010. Low nibble = lower K index.
            uint32_t w = 0;
            w |= ((v0.x < -EPSF) ? 0xAu : 0x2u);
            w |= ((v0.y < -EPSF) ? 0xAu : 0x2u) << 4;
            w |= ((v0.z < -EPSF) ? 0xAu : 0x2u) << 8;
            w |= ((v0.w < -EPSF) ? 0xAu : 0x2u) << 12;
            w |= ((v1.x < -EPSF) ? 0xAu : 0x2u) << 16;
            w |= ((v1.y < -EPSF) ? 0xAu : 0x2u) << 20;
            w |= ((v1.z < -EPSF) ? 0xAu : 0x2u) << 24;
            w |= ((v1.w < -EPSF) ? 0xAu : 0x2u) << 28;
            dst[idx] = w;
        }
    }
}

// C = X4 * W4^T via v_mfma_f32_32x32x64_f8f6f4 (FMT=FP4, scale=1).
// 128x128 tile, 256 threads (4 waves, 2x2 of 64x64 per wave, each wave 2x2
// tiles of 32x32). BK = 256 fp4 elements = 128 bytes. global_load_lds
// staging (16B/lane) with XOR chunk swizzle (chunk q of row r holds global
// chunk q^(r&7)):
//   - staging keeps wave-uniform-base + lane*16 contiguity (swizzle applied
//     to the SOURCE address; coalescing preserved per 8-lane row group)
//   - compute-side ds_read_b128 is bank-conflict-free by construction
// Fragment: MFMA m (K window [64m,64m+64)), lane half h needs fp4 elements
// [64m+32h, 64m+32h+32) = 16B chunk g = 2m+h. Same indexing as i8 version.
#define GM 128
#define GN 128
#define GKB 128   // K-tile bytes per row (256 fp4 elements)
#define KB4 2048  // row stride in bytes (4096 fp4 / 2)

#define SCALE_ONE 0x7F7F7F7Fu  // e8m0 127 = 2^0 in every byte (opsel-proof)

__global__ __launch_bounds__(256, 3)
void fp4mfma_gemm(const char* __restrict__ x4, const char* __restrict__ w4,
                  float* __restrict__ out) {
    __shared__ char xs[GM * GKB];
    __shared__ char wsh[GN * GKB];

    const int t = threadIdx.x;
    const int lane = t & 63;
    const int wave = t >> 6;
    const int wm = (wave >> 1) * 64;
    const int wn = (wave & 1) * 64;
    const int row0 = blockIdx.y * GM;
    const int col0 = blockIdx.x * GN;
    const int lrow = lane & 31;
    const int half = lane >> 5;

    f32x16 acc[2][2];
#pragma unroll
    for (int r = 0; r < 2; ++r)
#pragma unroll
        for (int c = 0; c < 2; ++c)
#pragma unroll
            for (int e = 0; e < 16; ++e) acc[r][c][e] = 0.0f;

    // Operand tuples: FP4 uses the low 4 regs; upper 4 stay zero.
    i32x8 a[2], b[2];
#pragma unroll
    for (int r = 0; r < 2; ++r)
#pragma unroll
        for (int e = 0; e < 8; ++e) { a[r][e] = 0; b[r][e] = 0; }

    for (int kb = 0; kb < 2048; kb += GKB) {   // 16 K-tiles
        __syncthreads();
#pragma unroll
        for (int j = 0; j < 4; ++j) {
            int c = j * 256 + t;          // 16B chunk id, 0..1023
            int row = c >> 3;             // 0..127
            int q = c & 7;                // LDS slot chunk
            int qg = q ^ (row & 7);       // global chunk feeding this slot
            const char* srcx = x4 + (size_t)(row0 + row) * KB4 + kb + qg * 16;
            __builtin_amdgcn_global_load_lds((const uint32_t*)srcx,
                                             (uint32_t*)(xs + c * 16), 16, 0, 0);
            const char* srcw = w4 + (size_t)(col0 + row) * KB4 + kb + qg * 16;
            __builtin_amdgcn_global_load_lds((const uint32_t*)srcw,
                                             (uint32_t*)(wsh + c * 16), 16, 0, 0);
        }
        __syncthreads();

#pragma unroll
        for (int m = 0; m < 4; ++m) {     // 4 MFMAs of K=64 over this K-tile
            int g = 2 * m + half;         // 16B chunk this lane-half needs
#pragma unroll
            for (int r = 0; r < 2; ++r) {
                int row = wm + r * 32 + lrow;
                int qs = g ^ (row & 7);
                i32x4 av = *(const i32x4*)(xs + row * GKB + qs * 16);
                a[r][0] = av[0]; a[r][1] = av[1];
                a[r][2] = av[2]; a[r][3] = av[3];
            }
#pragma unroll
            for (int c = 0; c < 2; ++c) {
                int col = wn + c * 32 + lrow;
                int qs = g ^ (col & 7);
                i32x4 bv = *(const i32x4*)(wsh + col * GKB + qs * 16);
                b[c][0] = bv[0]; b[c][1] = bv[1];
                b[c][2] = bv[2]; b[c][3] = bv[3];
            }
#pragma unroll
            for (int r = 0; r < 2; ++r)
#pragma unroll
                for (int c = 0; c < 2; ++c)
                    acc[r][c] = __builtin_amdgcn_mfma_scale_f32_32x32x64_f8f6f4(
                        a[r], b[c], acc[r][c],
                        4, 4,                   // cbsz=FP4, blgp=FP4
                        0, SCALE_ONE,           // A: opsel, scale (=1.0)
                        0, SCALE_ONE);          // B: opsel, scale (=1.0)
        }
    }

    // C/D layout (32x32, shape-determined, dtype-independent):
    // col = lane&31, row = (reg&3) + 8*(reg>>2) + 4*(lane>>5)
#pragma unroll
    for (int r = 0; r < 2; ++r)
#pragma unroll
        for (int c = 0; c < 2; ++c)
#pragma unroll
            for (int e = 0; e < 16; ++e) {
                int rr = row0 + wm + r * 32 + (e & 3) + 8 * (e >> 2) + 4 * half;
                int cc = col0 + wn + c * 32 + lrow;
                out[(size_t)rr * 4096 + cc] = acc[r][c][e];
            }
}

// ===========================================================================
// PATH B (fallback if ws_size too small): R1 bit-pack + XOR/popcount GEMM
// (verified correct, 503 us) — kept verbatim for safety.
// ===========================================================================

__global__ __launch_bounds__(256)
void binarize_kernel(const float* __restrict__ src,
                     unsigned long long* __restrict__ dst, int n256) {
    int wave = blockIdx.x * 4 + (threadIdx.x >> 6);
    if (wave >= n256) return;
    int lane = threadIdx.x & 63;
    const float4* p = (const float4*)(src + (size_t)wave * 256);
    float4 v = p[lane];
    unsigned long long m0 = __ballot(v.x < -EPSF);
    unsigned long long m1 = __ballot(v.y < -EPSF);
    unsigned long long m2 = __ballot(v.z < -EPSF);
    unsigned long long m3 = __ballot(v.w < -EPSF);
    if (lane < 4) {
        unsigned long long m = (lane == 0) ? m0 : (lane == 1) ? m1
                             : (lane == 2) ? m2 : m3;
        dst[(size_t)wave * 4 + lane] = m;
    }
}

#define BM 128
#define BN 128
#define CHUNK_Q 8
#define NCHUNK 4
#define LDSS 9

__global__ __launch_bounds__(256, 2)
void bingemm_kernel(const uint4* __restrict__ xb, const uint4* __restrict__ wb,
                    float* __restrict__ out) {
    __shared__ uint4 xsl[BM * LDSS];
    __shared__ uint4 wsl[BN * LDSS];

    const int t  = threadIdx.x;
    const int tx = t & 15;
    const int ty = t >> 4;
    const int row0 = blockIdx.y * BM;
    const int col0 = blockIdx.x * BN;

    int acc[8][8];
#pragma unroll
    for (int a = 0; a < 8; ++a)
#pragma unroll
        for (int b = 0; b < 8; ++b) acc[a][b] = 0;

    const int srow = t >> 3;
    const int sq   = t & 7;

    for (int c = 0; c < NCHUNK; ++c) {
        __syncthreads();
#pragma unroll
        for (int k = 0; k < 4; ++k) {
            int r = srow + 32 * k;
            xsl[r * LDSS + sq] = xb[(size_t)(row0 + r) * 32 + c * CHUNK_Q + sq];
            wsl[r * LDSS + sq] = wb[(size_t)(col0 + r) * 32 + c * CHUNK_Q + sq];
        }
        __syncthreads();

#pragma unroll
        for (int q = 0; q < CHUNK_Q; ++q) {
            uint4 xq[8], wq[8];
#pragma unroll
            for (int ri = 0; ri < 8; ++ri)
                xq[ri] = xsl[(ty + 16 * ri) * LDSS + q];
#pragma unroll
            for (int cj = 0; cj < 8; ++cj)
                wq[cj] = wsl[(tx + 16 * cj) * LDSS + q];
#pragma unroll
            for (int ri = 0; ri < 8; ++ri)
#pragma unroll
                for (int cj = 0; cj < 8; ++cj) {
                    acc[ri][cj] += __builtin_popcount(xq[ri].x ^ wq[cj].x);
                    acc[ri][cj] += __builtin_popcount(xq[ri].y ^ wq[cj].y);
                    acc[ri][cj] += __builtin_popcount(xq[ri].z ^ wq[cj].z);
                    acc[ri][cj] += __builtin_popcount(xq[ri].w ^ wq[cj].w);
                }
        }
    }

#pragma unroll
    for (int ri = 0; ri < 8; ++ri) {
        size_t i = row0 + ty + 16 * ri;
#pragma unroll
        for (int cj = 0; cj < 8; ++cj) {
            int j = col0 + tx + 16 * cj;
            out[i * 4096 + j] = (float)(4096 - 2 * acc[ri][cj]);
        }
    }
}

// ===========================================================================
extern "C" void kernel_launch(void* const* d_in, const int* in_sizes, int n_in,
                              void* d_out, int out_size, void* d_ws, size_t ws_size,
                              hipStream_t stream) {
    const float* x = (const float*)d_in[0];   // [8192, 4096] fp32
    const float* w = (const float*)d_in[1];   // [4096, 4096] fp32
    float* out = (float*)d_out;

    const int M = 8192, N = 4096, K = 4096;
    const size_t need_fp4 = ((size_t)M * K + (size_t)N * K) / 2;  // 25.2 MB

    if (ws_size >= need_fp4) {
        char* x4 = (char*)d_ws;
        char* w4 = x4 + (size_t)M * K / 2;

        int n8x = (M * K) / 8;   // 4194304 u32 -> 4096 blocks
        int n8w = (N * K) / 8;   // 2097152 u32 -> 2048 blocks
        bin_fp4_kernel<<<n8x / 1024, 256, 0, stream>>>(
            (const float4*)x, (uint32_t*)x4, n8x);
        bin_fp4_kernel<<<n8w / 1024, 256, 0, stream>>>(
            (const float4*)w, (uint32_t*)w4, n8w);

        dim3 grid(N / GN, M / GM);  // (32, 64)
        fp4mfma_gemm<<<grid, 256, 0, stream>>>(x4, w4, out);
    } else {
        uint32_t* xbits = (uint32_t*)d_ws;
        uint32_t* wbits = xbits + (size_t)M * (K / 32);

        binarize_kernel<<<(M * K) / 1024, 256, 0, stream>>>(
            x, (unsigned long long*)xbits, (M * K) / 256);
        binarize_kernel<<<(N * K) / 1024, 256, 0, stream>>>(
            w, (unsigned long long*)wbits, (N * K) / 256);

        dim3 grid(N / BN, M / BM);
        bingemm_kernel<<<grid, 256, 0, stream>>>(
            (const uint4*)xbits, (const uint4*)wbits, out);
    }
}

// Round 2
// 329.249 us; speedup vs baseline: 1.2139x; 1.0027x over previous
//
#include <hip/hip_runtime.h>
#include <stdint.h>

#define EPSF 1e-20f

typedef __attribute__((ext_vector_type(4))) int i32x4;
typedef __attribute__((ext_vector_type(8))) int i32x8;
typedef __attribute__((ext_vector_type(16))) float f32x16;

// ===========================================================================
// PATH A (primary): binarize to ±1 FP4 (e2m1) + mfma_scale f8f6f4 GEMM.
// ±1 is exact in e2m1 (+1=0x2, -1=0xA); scales forced to 1.0 (e8m0 0x7F).
// This round: 256x256 tile, 8 waves, double-buffered LDS (128 KiB), stage
// of tile t+1 issued DURING compute of tile t (T3 "minimum 2-phase"),
// single __syncthreads per K-tile (its built-in vmcnt(0) drain is the only
// wait). Previous 128² version paid full load latency between 2 barriers
// per tile with zero overlap -> 33% MfmaUtil.
// ===========================================================================

// fp32 -> packed fp4 nibbles, 8 floats per u32. Stores 4B/lane coalesced.
__global__ __launch_bounds__(256)
void bin_fp4_kernel(const float4* __restrict__ src, uint32_t* __restrict__ dst,
                    int n8) {
    int base = blockIdx.x * 1024 + threadIdx.x;   // u32 output index
#pragma unroll
    for (int j = 0; j < 4; ++j) {
        int idx = base + j * 256;
        if (idx < n8) {
            float4 v0 = src[2 * idx];
            float4 v1 = src[2 * idx + 1];
            // e2m1: +1.0 = 0b0010, -1.0 = 0b1010. Low nibble = lower K index.
            uint32_t w = 0;
            w |= ((v0.x < -EPSF) ? 0xAu : 0x2u);
            w |= ((v0.y < -EPSF) ? 0xAu : 0x2u) << 4;
            w |= ((v0.z < -EPSF) ? 0xAu : 0x2u) << 8;
            w |= ((v0.w < -EPSF) ? 0xAu : 0x2u) << 12;
            w |= ((v1.x < -EPSF) ? 0xAu : 0x2u) << 16;
            w |= ((v1.y < -EPSF) ? 0xAu : 0x2u) << 20;
            w |= ((v1.z < -EPSF) ? 0xAu : 0x2u) << 24;
            w |= ((v1.w < -EPSF) ? 0xAu : 0x2u) << 28;
            dst[idx] = w;
        }
    }
}

#define SCALE_ONE 0x7F7F7F7Fu  // e8m0 127 = 2^0 in every byte (opsel-proof)

// C = X4 * W4^T via v_mfma_f32_32x32x64_f8f6f4 (FMT=FP4, scale=1).
// 256x256 tile, 512 threads = 8 waves (2M x 4N), per-wave 128x64 output
// (4x2 tiles of 32x32). K-tile = 256 fp4 elements = 128 B/row.
// LDS: 2 buffers x (A 32KB | B 32KB) = 128 KiB.
// XOR chunk swizzle (16B chunk q of row r holds global chunk q^(r&7)):
// source-side swizzle keeps global_load_lds's linear-dest requirement while
// making compute-side ds_read_b128 spread across bank groups.
// Pipeline: per K-tile, the 8 stage loads for tile t+1 are issued 2-per-phase
// interleaved with the 4 compute slices of tile t; one __syncthreads at the
// end of the tile (drains vmcnt(0) + lgkmcnt(0)) is the only barrier.
__global__ __launch_bounds__(512, 2)
void fp4mfma_gemm256(const char* __restrict__ x4, const char* __restrict__ w4,
                     float* __restrict__ out) {
    __shared__ char lds[2][65536];   // [buf][ A: 0..32767 | B: 32768..65535 ]

    const int t = threadIdx.x;
    const int lane = t & 63;
    const int wave = t >> 6;
    const int wm = (wave >> 2) * 128;   // 0 or 128
    const int wn = (wave & 3) * 64;     // 0,64,128,192
    const int row0 = blockIdx.y * 256;
    const int col0 = blockIdx.x * 256;
    const int lrow = lane & 31;
    const int half = lane >> 5;

    const char* xbase = x4 + (size_t)row0 * 2048;  // 2048 B = 4096 fp4 per row
    const char* wbase = w4 + (size_t)col0 * 2048;

    // Staging constants: 2048 16B-chunks per 32KB tile, 4 per thread.
    // chunk id cid -> LDS slot cid*16; source chunk = (cid&7)^(row&7).
    int goff[4], loff[4];
#pragma unroll
    for (int j = 0; j < 4; ++j) {
        int cid = j * 512 + t;              // 0..2047
        int crow = cid >> 3;                // 0..255
        int cqg = (cid & 7) ^ (crow & 7);   // global chunk feeding this slot
        goff[j] = crow * 2048 + cqg * 16;
        loff[j] = cid * 16;
    }

    f32x16 acc[4][2];
#pragma unroll
    for (int r = 0; r < 4; ++r)
#pragma unroll
        for (int c = 0; c < 2; ++c)
#pragma unroll
            for (int e = 0; e < 16; ++e) acc[r][c][e] = 0.0f;

    // FP4 operands use the low 4 regs of the 8-reg tuple; upper 4 stay 0.
    i32x8 a[4], b[2];
#pragma unroll
    for (int r = 0; r < 4; ++r)
#pragma unroll
        for (int e = 0; e < 8; ++e) a[r][e] = 0;
#pragma unroll
    for (int c = 0; c < 2; ++c)
#pragma unroll
        for (int e = 0; e < 8; ++e) b[c][e] = 0;

    const int laneA = (wm + lrow) * 128;   // byte base of this lane's A rows
    const int laneB = (wn + lrow) * 128;

    // Prologue: stage K-tile 0 into buf 0; __syncthreads drains vmcnt(0).
#pragma unroll
    for (int j = 0; j < 4; ++j) {
        __builtin_amdgcn_global_load_lds((const uint32_t*)(xbase + goff[j]),
                                         (uint32_t*)(&lds[0][0] + loff[j]),
                                         16, 0, 0);
        __builtin_amdgcn_global_load_lds((const uint32_t*)(wbase + goff[j]),
                                         (uint32_t*)(&lds[0][0] + 32768 + loff[j]),
                                         16, 0, 0);
    }
    __syncthreads();

    for (int kt = 0; kt < 16; ++kt) {
        const int cur = kt & 1;
        const char* curA = &lds[cur][0];
        const char* curB = &lds[cur][0] + 32768;
        char* nxt = &lds[cur ^ 1][0];
        const int kbn = (kt + 1) * 128;     // byte offset of next K-tile
        const bool stage = (kt < 15);

#pragma unroll
        for (int m = 0; m < 4; ++m) {
            // Issue next-tile staging early so HBM/L2 latency hides under
            // this tile's MFMAs. Writes go to the buffer whose readers all
            // passed the previous __syncthreads.
            if (stage) {
                __builtin_amdgcn_global_load_lds(
                    (const uint32_t*)(xbase + goff[m] + kbn),
                    (uint32_t*)(nxt + loff[m]), 16, 0, 0);
                __builtin_amdgcn_global_load_lds(
                    (const uint32_t*)(wbase + goff[m] + kbn),
                    (uint32_t*)(nxt + 32768 + loff[m]), 16, 0, 0);
            }

            // Slice m covers fp4 k-elements [64m, 64m+64): lane half h reads
            // 16B chunk g = 2m+h, at swizzled slot g^(row&7) (row&7==lrow&7).
            const int qs16 = (((2 * m + half) ^ (lrow & 7)) << 4);
#pragma unroll
            for (int r = 0; r < 4; ++r) {
                i32x4 av = *(const i32x4*)(curA + laneA + r * 4096 + qs16);
                a[r][0] = av[0]; a[r][1] = av[1];
                a[r][2] = av[2]; a[r][3] = av[3];
            }
#pragma unroll
            for (int c = 0; c < 2; ++c) {
                i32x4 bv = *(const i32x4*)(curB + laneB + c * 4096 + qs16);
                b[c][0] = bv[0]; b[c][1] = bv[1];
                b[c][2] = bv[2]; b[c][3] = bv[3];
            }

            __builtin_amdgcn_s_setprio(1);
#pragma unroll
            for (int r = 0; r < 4; ++r)
#pragma unroll
                for (int c = 0; c < 2; ++c)
                    acc[r][c] = __builtin_amdgcn_mfma_scale_f32_32x32x64_f8f6f4(
                        a[r], b[c], acc[r][c],
                        4, 4,                   // cbsz=FP4, blgp=FP4
                        0, SCALE_ONE,           // A: opsel, scale (=1.0)
                        0, SCALE_ONE);          // B: opsel, scale (=1.0)
            __builtin_amdgcn_s_setprio(0);
        }
        // One barrier per K-tile: drains vmcnt(0) (staged tile landed) and
        // lgkmcnt, and fences buffer reuse.
        __syncthreads();
    }

    // C/D layout (32x32, shape-determined, dtype-independent):
    // col = lane&31, row = (reg&3) + 8*(reg>>2) + 4*(lane>>5)
#pragma unroll
    for (int r = 0; r < 4; ++r)
#pragma unroll
        for (int c = 0; c < 2; ++c)
#pragma unroll
            for (int e = 0; e < 16; ++e) {
                int rr = row0 + wm + r * 32 + (e & 3) + 8 * (e >> 2) + 4 * half;
                int cc = col0 + wn + c * 32 + lrow;
                out[(size_t)rr * 4096 + cc] = acc[r][c][e];
            }
}

// ===========================================================================
// PATH B (fallback if ws_size too small): R1 bit-pack + XOR/popcount GEMM
// (verified correct) — kept verbatim for safety.
// ===========================================================================

__global__ __launch_bounds__(256)
void binarize_kernel(const float* __restrict__ src,
                     unsigned long long* __restrict__ dst, int n256) {
    int wave = blockIdx.x * 4 + (threadIdx.x >> 6);
    if (wave >= n256) return;
    int lane = threadIdx.x & 63;
    const float4* p = (const float4*)(src + (size_t)wave * 256);
    float4 v = p[lane];
    unsigned long long m0 = __ballot(v.x < -EPSF);
    unsigned long long m1 = __ballot(v.y < -EPSF);
    unsigned long long m2 = __ballot(v.z < -EPSF);
    unsigned long long m3 = __ballot(v.w < -EPSF);
    if (lane < 4) {
        unsigned long long m = (lane == 0) ? m0 : (lane == 1) ? m1
                             : (lane == 2) ? m2 : m3;
        dst[(size_t)wave * 4 + lane] = m;
    }
}

#define BM 128
#define BN 128
#define CHUNK_Q 8
#define NCHUNK 4
#define LDSS 9

__global__ __launch_bounds__(256, 2)
void bingemm_kernel(const uint4* __restrict__ xb, const uint4* __restrict__ wb,
                    float* __restrict__ out) {
    __shared__ uint4 xsl[BM * LDSS];
    __shared__ uint4 wsl[BN * LDSS];

    const int t  = threadIdx.x;
    const int tx = t & 15;
    const int ty = t >> 4;
    const int row0 = blockIdx.y * BM;
    const int col0 = blockIdx.x * BN;

    int acc[8][8];
#pragma unroll
    for (int a = 0; a < 8; ++a)
#pragma unroll
        for (int b = 0; b < 8; ++b) acc[a][b] = 0;

    const int srow = t >> 3;
    const int sq   = t & 7;

    for (int c = 0; c < NCHUNK; ++c) {
        __syncthreads();
#pragma unroll
        for (int k = 0; k < 4; ++k) {
            int r = srow + 32 * k;
            xsl[r * LDSS + sq] = xb[(size_t)(row0 + r) * 32 + c * CHUNK_Q + sq];
            wsl[r * LDSS + sq] = wb[(size_t)(col0 + r) * 32 + c * CHUNK_Q + sq];
        }
        __syncthreads();

#pragma unroll
        for (int q = 0; q < CHUNK_Q; ++q) {
            uint4 xq[8], wq[8];
#pragma unroll
            for (int ri = 0; ri < 8; ++ri)
                xq[ri] = xsl[(ty + 16 * ri) * LDSS + q];
#pragma unroll
            for (int cj = 0; cj < 8; ++cj)
                wq[cj] = wsl[(tx + 16 * cj) * LDSS + q];
#pragma unroll
            for (int ri = 0; ri < 8; ++ri)
#pragma unroll
                for (int cj = 0; cj < 8; ++cj) {
                    acc[ri][cj] += __builtin_popcount(xq[ri].x ^ wq[cj].x);
                    acc[ri][cj] += __builtin_popcount(xq[ri].y ^ wq[cj].y);
                    acc[ri][cj] += __builtin_popcount(xq[ri].z ^ wq[cj].z);
                    acc[ri][cj] += __builtin_popcount(xq[ri].w ^ wq[cj].w);
                }
        }
    }

#pragma unroll
    for (int ri = 0; ri < 8; ++ri) {
        size_t i = row0 + ty + 16 * ri;
#pragma unroll
        for (int cj = 0; cj < 8; ++cj) {
            int j = col0 + tx + 16 * cj;
            out[i * 4096 + j] = (float)(4096 - 2 * acc[ri][cj]);
        }
    }
}

// ===========================================================================
extern "C" void kernel_launch(void* const* d_in, const int* in_sizes, int n_in,
                              void* d_out, int out_size, void* d_ws, size_t ws_size,
                              hipStream_t stream) {
    const float* x = (const float*)d_in[0];   // [8192, 4096] fp32
    const float* w = (const float*)d_in[1];   // [4096, 4096] fp32
    float* out = (float*)d_out;

    const int M = 8192, N = 4096, K = 4096;
    const size_t need_fp4 = ((size_t)M * K + (size_t)N * K) / 2;  // 25.2 MB

    if (ws_size >= need_fp4) {
        char* x4 = (char*)d_ws;
        char* w4 = x4 + (size_t)M * K / 2;

        int n8x = (M * K) / 8;   // 4194304 u32 -> 4096 blocks
        int n8w = (N * K) / 8;   // 2097152 u32 -> 2048 blocks
        bin_fp4_kernel<<<n8x / 1024, 256, 0, stream>>>(
            (const float4*)x, (uint32_t*)x4, n8x);
        bin_fp4_kernel<<<n8w / 1024, 256, 0, stream>>>(
            (const float4*)w, (uint32_t*)w4, n8w);

        dim3 grid(N / 256, M / 256);  // (16, 32) = 512 blocks
        fp4mfma_gemm256<<<grid, 512, 0, stream>>>(x4, w4, out);
    } else {
        uint32_t* xbits = (uint32_t*)d_ws;
        uint32_t* wbits = xbits + (size_t)M * (K / 32);

        binarize_kernel<<<(M * K) / 1024, 256, 0, stream>>>(
            x, (unsigned long long*)xbits, (M * K) / 256);
        binarize_kernel<<<(N * K) / 1024, 256, 0, stream>>>(
            w, (unsigned long long*)wbits, (N * K) / 256);

        dim3 grid(N / BN, M / BM);
        bingemm_kernel<<<grid, 256, 0, stream>>>(
            (const uint4*)xbits, (const uint4*)wbits, out);
    }
}

// Round 3
// 326.183 us; speedup vs baseline: 1.2253x; 1.0094x over previous
//
#include <hip/hip_runtime.h>
#include <stdint.h>

#define EPSF 1e-20f

typedef __attribute__((ext_vector_type(4))) int i32x4;
typedef __attribute__((ext_vector_type(8))) int i32x8;
typedef __attribute__((ext_vector_type(16))) float f32x16;

// ===========================================================================
// PATH A (primary): binarize to ±1 FP4 (e2m1) + mfma_scale f8f6f4 GEMM.
// ±1 is exact in e2m1 (+1=0x2, -1=0xA); scales forced to 1.0 (e8m0 0x7F).
// Round 3: counted-vmcnt pipeline (T4). The R2 version still drained
// vmcnt(0) at its per-tile __syncthreads (1 block/CU -> no TLP to hide it;
// MfmaUtil stuck at 33%). Now: 2 half-phases per K-tile, 8x8KB row-group
// staging, raw s_barrier + counted s_waitcnt vmcnt(2)/vmcnt(4) so staged
// loads stay in flight ACROSS barriers. Never vmcnt(0) in the main loop.
// ===========================================================================

// fp32 -> packed fp4 nibbles, 8 floats per u32. Stores 4B/lane coalesced.
__global__ __launch_bounds__(256)
void bin_fp4_kernel(const float4* __restrict__ src, uint32_t* __restrict__ dst,
                    int n8) {
    int base = blockIdx.x * 1024 + threadIdx.x;   // u32 output index
#pragma unroll
    for (int j = 0; j < 4; ++j) {
        int idx = base + j * 256;
        if (idx < n8) {
            float4 v0 = src[2 * idx];
            float4 v1 = src[2 * idx + 1];
            // e2m1: +1.0 = 0b0010, -1.0 = 0b1010. Low nibble = lower K index.
            uint32_t w = 0;
            w |= ((v0.x < -EPSF) ? 0xAu : 0x2u);
            w |= ((v0.y < -EPSF) ? 0xAu : 0x2u) << 4;
            w |= ((v0.z < -EPSF) ? 0xAu : 0x2u) << 8;
            w |= ((v0.w < -EPSF) ? 0xAu : 0x2u) << 12;
            w |= ((v1.x < -EPSF) ? 0xAu : 0x2u) << 16;
            w |= ((v1.y < -EPSF) ? 0xAu : 0x2u) << 20;
            w |= ((v1.z < -EPSF) ? 0xAu : 0x2u) << 24;
            w |= ((v1.w < -EPSF) ? 0xAu : 0x2u) << 28;
            dst[idx] = w;
        }
    }
}

#define SCALE_ONE 0x7F7F7F7Fu  // e8m0 127 = 2^0 in every byte (opsel-proof)

// C = X4 * W4^T via v_mfma_f32_32x32x64_f8f6f4 (FMT=FP4, scale=1).
// 256x256 tile, 512 threads = 8 waves (2M x 4N), per-wave 128x64 output
// (4x2 tiles of 32x32). K-tile = 256 fp4 = 128 B/row; 16 K-tiles.
// LDS: dbuf[2] x (A 32KB | B 32KB) = 128 KiB (1 block/CU by design).
//
// Staging: 8 groups of 8KB per K-tile (A0..A3 = 64-row blocks of A,
// B0..B3 = 64-row blocks of B). Per thread per group: one 16B
// global_load_lds; dest = group*8192 + t*16 (wave-uniform base + lane*16,
// as required). Source carries the XOR chunk swizzle (slot q of row r is
// fed from global chunk q^(r&7)) so compute-side ds_read_b128 is spread
// across bank groups.
//
// Schedule per K-tile t (buffers: cur = t&1, nxt = cur^1):
//   H0: vmcnt(2); s_barrier; issue [A0,A2,B0,B1] of t+1 -> nxt;
//       compute acc rows 0,1 (reads A rows wm..wm+63 + B cols wn..wn+63;
//       B fragments kept in registers for H1)
//   H1: vmcnt(4); s_barrier; issue [B2,B3,A1,A3] of t+1 -> nxt;
//       compute acc rows 2,3 (reads A rows wm+64..wm+127; B from regs)
// vmcnt ledger (issue order is load-queue order):
//   at t H0, outstanding-after-needed = {A1,A3 of t} = 2 -> vmcnt(2)
//   at t H1, outstanding-after-needed = {H0's 4 issues} = 4 -> vmcnt(4)
// Overwrite safety: issues target nxt, whose last readers (tile t-1) all
// passed the H0 barrier of tile t; issues sit after that barrier.
// Cross-wave read safety: each wave certifies its own staged loads landed
// (vmcnt BEFORE the barrier), barrier publishes to all waves.
__global__ __launch_bounds__(512, 2)
void fp4mfma_gemm256(const char* __restrict__ x4, const char* __restrict__ w4,
                     float* __restrict__ out) {
    __shared__ char lds[2][65536];   // [buf][ A: 0..32767 | B: 32768..65535 ]

    const int t = threadIdx.x;
    const int lane = t & 63;
    const int wave = t >> 6;
    const int wm = (wave >> 2) * 128;   // 0 or 128
    const int wn = (wave & 3) * 64;     // 0,64,128,192
    const int row0 = blockIdx.y * 256;
    const int col0 = blockIdx.x * 256;
    const int lrow = lane & 31;
    const int half = lane >> 5;

    const char* xbase = x4 + (size_t)row0 * 2048;  // 2048 B = 4096 fp4 per row
    const char* wbase = w4 + (size_t)col0 * 2048;

    // Staging per-thread constants (group-relative; row = g*64 + (t>>3)).
    const int srow = t >> 3;                   // 0..63 within a 64-row group
    const int sqg  = (t & 7) ^ (srow & 7);     // source chunk for LDS slot t&7
    const int gsrc = srow * 2048 + sqg * 16;   // + g*131072 + kb
    const int gdst = t * 16;                   // + g*8192  (linear in lane)

    f32x16 acc[4][2];
#pragma unroll
    for (int r = 0; r < 4; ++r)
#pragma unroll
        for (int c = 0; c < 2; ++c)
#pragma unroll
            for (int e = 0; e < 16; ++e) acc[r][c][e] = 0.0f;

    // FP4 operands use the low 4 regs of the 8-reg tuple; upper 4 stay 0.
    i32x8 a8[2], b8[2];
#pragma unroll
    for (int r = 0; r < 2; ++r)
#pragma unroll
        for (int e = 0; e < 8; ++e) { a8[r][e] = 0; b8[r][e] = 0; }

    // Per-slice swizzled chunk offset (row&7 == lrow&7 for all our rows).
    int qs16[4];
#pragma unroll
    for (int m = 0; m < 4; ++m)
        qs16[m] = (((2 * m + half) ^ (lrow & 7)) << 4);

    const int aoff = (wm + lrow) * 128;   // + (2*hf+r)*4096 + qs16[m]
    const int boff = (wn + lrow) * 128;   // + c*4096 + qs16[m]

#define ISSUE_A(buf, g, kb)                                                   \
    __builtin_amdgcn_global_load_lds(                                         \
        (const uint32_t*)(xbase + (g) * 131072 + gsrc + (kb)),                \
        (uint32_t*)((buf) + (g) * 8192 + gdst), 16, 0, 0)
#define ISSUE_B(buf, g, kb)                                                   \
    __builtin_amdgcn_global_load_lds(                                         \
        (const uint32_t*)(wbase + (g) * 131072 + gsrc + (kb)),                \
        (uint32_t*)((buf) + 32768 + (g) * 8192 + gdst), 16, 0, 0)

    // Prologue: stage tile 0 in the exact steady-state issue order.
    {
        char* b0 = &lds[0][0];
        ISSUE_A(b0, 0, 0); ISSUE_A(b0, 2, 0); ISSUE_B(b0, 0, 0); ISSUE_B(b0, 1, 0);
        ISSUE_B(b0, 2, 0); ISSUE_B(b0, 3, 0); ISSUE_A(b0, 1, 0); ISSUE_A(b0, 3, 0);
    }

    i32x4 bv[2][4];   // B fragments, loaded in H0, reused in H1

    for (int kt = 0; kt < 16; ++kt) {
        char* cbuf = &lds[kt & 1][0];
        char* nbuf = &lds[(kt & 1) ^ 1][0];
        const int kb = (kt + 1) * 128;
        const bool st = (kt < 15);

        // ---------------- H0: acc rows 0,1 ----------------
        asm volatile("s_waitcnt vmcnt(2)" ::: "memory");
        __builtin_amdgcn_s_barrier();
        asm volatile("" ::: "memory");   // pin LDS reads below the barrier
        if (st) {
            ISSUE_A(nbuf, 0, kb); ISSUE_A(nbuf, 2, kb);
            ISSUE_B(nbuf, 0, kb); ISSUE_B(nbuf, 1, kb);
        }
#pragma unroll
        for (int m = 0; m < 4; ++m) {
#pragma unroll
            for (int r = 0; r < 2; ++r) {
                i32x4 av = *(const i32x4*)(cbuf + aoff + r * 4096 + qs16[m]);
                a8[r][0] = av[0]; a8[r][1] = av[1];
                a8[r][2] = av[2]; a8[r][3] = av[3];
            }
#pragma unroll
            for (int c = 0; c < 2; ++c) {
                bv[c][m] = *(const i32x4*)(cbuf + 32768 + boff + c * 4096 + qs16[m]);
                b8[c][0] = bv[c][m][0]; b8[c][1] = bv[c][m][1];
                b8[c][2] = bv[c][m][2]; b8[c][3] = bv[c][m][3];
            }
            __builtin_amdgcn_s_setprio(1);
#pragma unroll
            for (int r = 0; r < 2; ++r)
#pragma unroll
                for (int c = 0; c < 2; ++c)
                    acc[r][c] = __builtin_amdgcn_mfma_scale_f32_32x32x64_f8f6f4(
                        a8[r], b8[c], acc[r][c],
                        4, 4, 0, SCALE_ONE, 0, SCALE_ONE);
            __builtin_amdgcn_s_setprio(0);
        }

        // ---------------- H1: acc rows 2,3 ----------------
        if (st) { asm volatile("s_waitcnt vmcnt(4)" ::: "memory"); }
        else    { asm volatile("s_waitcnt vmcnt(0)" ::: "memory"); }
        __builtin_amdgcn_s_barrier();
        asm volatile("" ::: "memory");
        if (st) {
            ISSUE_B(nbuf, 2, kb); ISSUE_B(nbuf, 3, kb);
            ISSUE_A(nbuf, 1, kb); ISSUE_A(nbuf, 3, kb);
        }
#pragma unroll
        for (int m = 0; m < 4; ++m) {
#pragma unroll
            for (int r = 0; r < 2; ++r) {
                i32x4 av = *(const i32x4*)(cbuf + aoff + (2 + r) * 4096 + qs16[m]);
                a8[r][0] = av[0]; a8[r][1] = av[1];
                a8[r][2] = av[2]; a8[r][3] = av[3];
            }
#pragma unroll
            for (int c = 0; c < 2; ++c) {
                b8[c][0] = bv[c][m][0]; b8[c][1] = bv[c][m][1];
                b8[c][2] = bv[c][m][2]; b8[c][3] = bv[c][m][3];
            }
            __builtin_amdgcn_s_setprio(1);
#pragma unroll
            for (int r = 0; r < 2; ++r)
#pragma unroll
                for (int c = 0; c < 2; ++c)
                    acc[2 + r][c] = __builtin_amdgcn_mfma_scale_f32_32x32x64_f8f6f4(
                        a8[r], b8[c], acc[2 + r][c],
                        4, 4, 0, SCALE_ONE, 0, SCALE_ONE);
            __builtin_amdgcn_s_setprio(0);
        }
    }
#undef ISSUE_A
#undef ISSUE_B

    // C/D layout (32x32, shape-determined, dtype-independent):
    // col = lane&31, row = (reg&3) + 8*(reg>>2) + 4*(lane>>5)
#pragma unroll
    for (int r = 0; r < 4; ++r)
#pragma unroll
        for (int c = 0; c < 2; ++c)
#pragma unroll
            for (int e = 0; e < 16; ++e) {
                int rr = row0 + wm + r * 32 + (e & 3) + 8 * (e >> 2) + 4 * half;
                int cc = col0 + wn + c * 32 + lrow;
                out[(size_t)rr * 4096 + cc] = acc[r][c][e];
            }
}

// ===========================================================================
// PATH B (fallback if ws_size too small): R1 bit-pack + XOR/popcount GEMM
// (verified correct) — kept verbatim for safety.
// ===========================================================================

__global__ __launch_bounds__(256)
void binarize_kernel(const float* __restrict__ src,
                     unsigned long long* __restrict__ dst, int n256) {
    int wave = blockIdx.x * 4 + (threadIdx.x >> 6);
    if (wave >= n256) return;
    int lane = threadIdx.x & 63;
    const float4* p = (const float4*)(src + (size_t)wave * 256);
    float4 v = p[lane];
    unsigned long long m0 = __ballot(v.x < -EPSF);
    unsigned long long m1 = __ballot(v.y < -EPSF);
    unsigned long long m2 = __ballot(v.z < -EPSF);
    unsigned long long m3 = __ballot(v.w < -EPSF);
    if (lane < 4) {
        unsigned long long m = (lane == 0) ? m0 : (lane == 1) ? m1
                             : (lane == 2) ? m2 : m3;
        dst[(size_t)wave * 4 + lane] = m;
    }
}

#define BM 128
#define BN 128
#define CHUNK_Q 8
#define NCHUNK 4
#define LDSS 9

__global__ __launch_bounds__(256, 2)
void bingemm_kernel(const uint4* __restrict__ xb, const uint4* __restrict__ wb,
                    float* __restrict__ out) {
    __shared__ uint4 xsl[BM * LDSS];
    __shared__ uint4 wsl[BN * LDSS];

    const int t  = threadIdx.x;
    const int tx = t & 15;
    const int ty = t >> 4;
    const int row0 = blockIdx.y * BM;
    const int col0 = blockIdx.x * BN;

    int acc[8][8];
#pragma unroll
    for (int a = 0; a < 8; ++a)
#pragma unroll
        for (int b = 0; b < 8; ++b) acc[a][b] = 0;

    const int srow = t >> 3;
    const int sq   = t & 7;

    for (int c = 0; c < NCHUNK; ++c) {
        __syncthreads();
#pragma unroll
        for (int k = 0; k < 4; ++k) {
            int r = srow + 32 * k;
            xsl[r * LDSS + sq] = xb[(size_t)(row0 + r) * 32 + c * CHUNK_Q + sq];
            wsl[r * LDSS + sq] = wb[(size_t)(col0 + r) * 32 + c * CHUNK_Q + sq];
        }
        __syncthreads();

#pragma unroll
        for (int q = 0; q < CHUNK_Q; ++q) {
            uint4 xq[8], wq[8];
#pragma unroll
            for (int ri = 0; ri < 8; ++ri)
                xq[ri] = xsl[(ty + 16 * ri) * LDSS + q];
#pragma unroll
            for (int cj = 0; cj < 8; ++cj)
                wq[cj] = wsl[(tx + 16 * cj) * LDSS + q];
#pragma unroll
            for (int ri = 0; ri < 8; ++ri)
#pragma unroll
                for (int cj = 0; cj < 8; ++cj) {
                    acc[ri][cj] += __builtin_popcount(xq[ri].x ^ wq[cj].x);
                    acc[ri][cj] += __builtin_popcount(xq[ri].y ^ wq[cj].y);
                    acc[ri][cj] += __builtin_popcount(xq[ri].z ^ wq[cj].z);
                    acc[ri][cj] += __builtin_popcount(xq[ri].w ^ wq[cj].w);
                }
        }
    }

#pragma unroll
    for (int ri = 0; ri < 8; ++ri) {
        size_t i = row0 + ty + 16 * ri;
#pragma unroll
        for (int cj = 0; cj < 8; ++cj) {
            int j = col0 + tx + 16 * cj;
            out[i * 4096 + j] = (float)(4096 - 2 * acc[ri][cj]);
        }
    }
}

// ===========================================================================
extern "C" void kernel_launch(void* const* d_in, const int* in_sizes, int n_in,
                              void* d_out, int out_size, void* d_ws, size_t ws_size,
                              hipStream_t stream) {
    const float* x = (const float*)d_in[0];   // [8192, 4096] fp32
    const float* w = (const float*)d_in[1];   // [4096, 4096] fp32
    float* out = (float*)d_out;

    const int M = 8192, N = 4096, K = 4096;
    const size_t need_fp4 = ((size_t)M * K + (size_t)N * K) / 2;  // 25.2 MB

    if (ws_size >= need_fp4) {
        char* x4 = (char*)d_ws;
        char* w4 = x4 + (size_t)M * K / 2;

        int n8x = (M * K) / 8;   // 4194304 u32 -> 4096 blocks
        int n8w = (N * K) / 8;   // 2097152 u32 -> 2048 blocks
        bin_fp4_kernel<<<n8x / 1024, 256, 0, stream>>>(
            (const float4*)x, (uint32_t*)x4, n8x);
        bin_fp4_kernel<<<n8w / 1024, 256, 0, stream>>>(
            (const float4*)w, (uint32_t*)w4, n8w);

        dim3 grid(N / 256, M / 256);  // (16, 32) = 512 blocks
        fp4mfma_gemm256<<<grid, 512, 0, stream>>>(x4, w4, out);
    } else {
        uint32_t* xbits = (uint32_t*)d_ws;
        uint32_t* wbits = xbits + (size_t)M * (K / 32);

        binarize_kernel<<<(M * K) / 1024, 256, 0, stream>>>(
            x, (unsigned long long*)xbits, (M * K) / 256);
        binarize_kernel<<<(N * K) / 1024, 256, 0, stream>>>(
            w, (unsigned long long*)wbits, (N * K) / 256);

        dim3 grid(N / BN, M / BM);
        bingemm_kernel<<<grid, 256, 0, stream>>>(
            (const uint4*)xbits, (const uint4*)wbits, out);
    }
}